// Round 2
// baseline (80.103 us; speedup 1.0000x reference)
//
#include <hip/hip_runtime.h>
#include <float.h>

#define B_    64
#define C_    1000
#define HW_   784
#define HW4_  196            // HW_/4 float4s per channel plane
#define TOPK_ 25
#define NB_GATHER (B_ * TOPK_)   // 1600

// ---------------------------------------------------------------------------
// Kernel A: one 64-lane wave per batch row.
//   - top-25 argmax of main_out[b,:] entirely in registers (16 vals/lane)
//   - sum of p[b,0,:,:] via float4 + wave shuffle
//   - block 0 zeroes the ticket counter for kernel B (fresh every call ->
//     graph-replay deterministic)
// ---------------------------------------------------------------------------
__global__ __launch_bounds__(64) void topk_psum_kernel(
        const float* __restrict__ p,
        const float* __restrict__ main_out,
        int*   __restrict__ idx_out,
        float* __restrict__ psum_out,
        int*   __restrict__ counter) {
    const int b    = blockIdx.x;
    const int lane = threadIdx.x;

    if (b == 0 && lane == 0) *counter = 0;

    // Load logits: lane holds indices lane + 64*j, j = 0..15 (covers 1024 >= 1000)
    float v[16];
    #pragma unroll
    for (int j = 0; j < 16; ++j) {
        int i = lane + 64 * j;
        v[j] = (i < C_) ? main_out[b * C_ + i] : -FLT_MAX;
    }

    for (int k = 0; k < TOPK_; ++k) {
        // per-lane argmax; strict '>' keeps smallest j (= smallest global idx)
        float best = -FLT_MAX;
        int   bj   = 0;
        #pragma unroll
        for (int j = 0; j < 16; ++j)
            if (v[j] > best) { best = v[j]; bj = j; }
        int bi = lane + 64 * bj;

        // wave argmax, tie-break to smaller global index (mirrors lax.top_k)
        #pragma unroll
        for (int off = 32; off > 0; off >>= 1) {
            float ov = __shfl_xor(best, off);
            int   oi = __shfl_xor(bi,   off);
            if (ov > best || (ov == best && oi < bi)) { best = ov; bi = oi; }
        }

        if (lane == 0) idx_out[b * TOPK_ + k] = bi;

        // zap winner (static unrolled indexing -> stays in VGPRs)
        #pragma unroll
        for (int j = 0; j < 16; ++j)
            if (lane + 64 * j == bi) v[j] = -FLT_MAX;
    }

    // sum p[b,0,:,:] — 196 float4s, wave-strided
    const float4* pb = (const float4*)(p + (size_t)b * HW_);
    float s = 0.0f;
    for (int j = lane; j < HW4_; j += 64) {
        float4 q = pb[j];
        s += q.x + q.y + q.z + q.w;
    }
    #pragma unroll
    for (int off = 32; off > 0; off >>= 1) s += __shfl_xor(s, off);
    if (lane == 0) psum_out[b] = s;
}

// ---------------------------------------------------------------------------
// Kernel B: one 64-lane wave per (b,k) pair: sum features[b, idx[b,k], :, :].
// The last block to finish (ticket pattern, device-scope atomics) reduces all
// 1600 partials + 64 p-sums in a fixed order (bit-deterministic) and writes
// the scalar output.
// ---------------------------------------------------------------------------
__global__ __launch_bounds__(64) void gather_finalize_kernel(
        const float* __restrict__ features,
        const int*   __restrict__ idx,
        const float* __restrict__ psum,
        float*       __restrict__ partial,
        int*         __restrict__ counter,
        float*       __restrict__ out) {
    const int g    = blockIdx.x;          // 0 .. 1599
    const int lane = threadIdx.x;
    const int b    = g / TOPK_;
    const int c    = idx[g];

    const float4* f = (const float4*)(features + ((size_t)b * C_ + (size_t)c) * HW_);
    float s = 0.0f;
    for (int j = lane; j < HW4_; j += 64) {
        float4 q = f[j];
        s += q.x + q.y + q.z + q.w;
    }
    #pragma unroll
    for (int off = 32; off > 0; off >>= 1) s += __shfl_xor(s, off);

    int ticket = 0;
    if (lane == 0) {
        __hip_atomic_store(&partial[g], s, __ATOMIC_RELEASE, __HIP_MEMORY_SCOPE_AGENT);
        ticket = __hip_atomic_fetch_add(counter, 1, __ATOMIC_ACQ_REL, __HIP_MEMORY_SCOPE_AGENT);
    }
    ticket = __shfl(ticket, 0);

    if (ticket == NB_GATHER - 1) {
        // all other blocks have published their partials (release->acquire)
        double acc = 0.0;
        for (int i = lane; i < NB_GATHER; i += 64)
            acc += (double)__hip_atomic_load(&partial[i], __ATOMIC_ACQUIRE,
                                             __HIP_MEMORY_SCOPE_AGENT);
        for (int i = lane; i < B_; i += 64)
            acc += (double)psum[i];
        #pragma unroll
        for (int off = 32; off > 0; off >>= 1) acc += __shfl_xor(acc, off);
        if (lane == 0) out[0] = (float)(acc / (double)(B_ * HW_));
    }
}

extern "C" void kernel_launch(void* const* d_in, const int* in_sizes, int n_in,
                              void* d_out, int out_size, void* d_ws, size_t ws_size,
                              hipStream_t stream) {
    const float* p        = (const float*)d_in[0];   // [64,1,28,28]
    const float* main_out = (const float*)d_in[1];   // [64,1000]
    const float* features = (const float*)d_in[2];   // [64,1000,28,28]
    float*       out      = (float*)d_out;           // scalar

    // ws layout: counter (16B slot) | idx[1600] int | psum[64] f32 | partial[1600] f32
    char* w = (char*)d_ws;
    int*   counter = (int*)w;                         w += 16;
    int*   idx     = (int*)w;                         w += NB_GATHER * sizeof(int);
    float* psum    = (float*)w;                       w += B_ * sizeof(float);
    float* partial = (float*)w;

    topk_psum_kernel<<<B_, 64, 0, stream>>>(p, main_out, idx, psum, counter);
    gather_finalize_kernel<<<NB_GATHER, 64, 0, stream>>>(features, idx, psum,
                                                         partial, counter, out);
}

// Round 3
// 35.724 us; speedup vs baseline: 2.2422x; 2.2422x over previous
//
#include <hip/hip_runtime.h>
#include <float.h>

#define B_    64
#define C_    1000
#define HW_   784
#define HW4_  196            // HW_/4 float4s per channel plane
#define TOPK_ 25
#define NB_   (B_ * TOPK_)   // 1600

// ---------------------------------------------------------------------------
// Kernel 1: one 64-lane wave per (b, k) pair. Each block independently
// recomputes row b's top-(k+1) in registers (no inter-block communication),
// then gathers and sums features[b, idx_k, :, :]. Block with k==0 also folds
// in the sum of p[b,0,:,:]. Plain stores only — no atomics, no LDS.
// ---------------------------------------------------------------------------
__global__ __launch_bounds__(64) void gather_topk_kernel(
        const float* __restrict__ p,
        const float* __restrict__ main_out,
        const float* __restrict__ features,
        float* __restrict__ fsum) {
    const int g    = blockIdx.x;          // 0 .. 1599
    const int b    = g / TOPK_;
    const int k    = g - b * TOPK_;
    const int lane = threadIdx.x;

    // Logits row in registers: lane holds indices lane + 64*j, j = 0..15
    float v[16];
    #pragma unroll
    for (int j = 0; j < 16; ++j) {
        int i = lane + 64 * j;
        v[j] = (i < C_) ? main_out[b * C_ + i] : -FLT_MAX;
    }

    // k+1 argmax rounds; after the loop `sel` is the k-th largest index.
    int sel = 0;
    for (int kk = 0; kk <= k; ++kk) {
        // per-lane argmax; ascending j + strict '>' keeps smallest global
        // index on ties (global idx = lane + 64*j is monotone in j)
        float best = -FLT_MAX;
        int   bj   = 0;
        #pragma unroll
        for (int j = 0; j < 16; ++j)
            if (v[j] > best) { best = v[j]; bj = j; }
        int bi = lane + 64 * bj;

        // wave argmax, tie-break to smaller global index (mirrors lax.top_k)
        #pragma unroll
        for (int off = 32; off > 0; off >>= 1) {
            float ov = __shfl_xor(best, off);
            int   oi = __shfl_xor(bi,   off);
            if (ov > best || (ov == best && oi < bi)) { best = ov; bi = oi; }
        }
        sel = bi;

        // zap winner (compile-time j indexing -> stays in VGPRs)
        #pragma unroll
        for (int j = 0; j < 16; ++j)
            if (lane + 64 * j == bi) v[j] = -FLT_MAX;
    }

    // gather + sum features[b, sel, :, :] — 196 float4s, wave-strided
    const float4* f = (const float4*)(features + ((size_t)b * C_ + (size_t)sel) * HW_);
    float s = 0.0f;
    for (int j = lane; j < HW4_; j += 64) {
        float4 q = f[j];
        s += q.x + q.y + q.z + q.w;
    }

    // k==0 block additionally sums p[b,0,:,:] (block-uniform branch)
    if (k == 0) {
        const float4* pb = (const float4*)(p + (size_t)b * HW_);
        for (int j = lane; j < HW4_; j += 64) {
            float4 q = pb[j];
            s += q.x + q.y + q.z + q.w;
        }
    }

    #pragma unroll
    for (int off = 32; off > 0; off >>= 1) s += __shfl_xor(s, off);
    if (lane == 0) fsum[g] = s;
}

// ---------------------------------------------------------------------------
// Kernel 2: one wave reduces the 1600 partials in a fixed order -> scalar.
// ---------------------------------------------------------------------------
__global__ __launch_bounds__(64) void finalize_kernel(
        const float* __restrict__ fsum,
        float*       __restrict__ out) {
    const int lane = threadIdx.x;
    double acc = 0.0;
    for (int i = lane; i < NB_; i += 64)
        acc += (double)fsum[i];
    #pragma unroll
    for (int off = 32; off > 0; off >>= 1) acc += __shfl_xor(acc, off);
    if (lane == 0) out[0] = (float)(acc / (double)(B_ * HW_));
}

extern "C" void kernel_launch(void* const* d_in, const int* in_sizes, int n_in,
                              void* d_out, int out_size, void* d_ws, size_t ws_size,
                              hipStream_t stream) {
    const float* p        = (const float*)d_in[0];   // [64,1,28,28]
    const float* main_out = (const float*)d_in[1];   // [64,1000]
    const float* features = (const float*)d_in[2];   // [64,1000,28,28]
    float*       out      = (float*)d_out;           // scalar

    float* fsum = (float*)d_ws;                      // 1600 floats

    gather_topk_kernel<<<NB_, 64, 0, stream>>>(p, main_out, features, fsum);
    finalize_kernel<<<1, 64, 0, stream>>>(fsum, out);
}